// Round 4
// baseline (79.861 us; speedup 1.0000x reference)
//
#include <hip/hip_runtime.h>

#define H 4096
#define W 4096
#define R 8              // output rows per block
#define TC 4             // cols per thread
#define TPB 256
#define STRIP (TPB*TC)   // 1024 cols per block
#define NSTRIP (W/STRIP) // 4
#define NBAND (H/R)      // 512
#define LN2 0.69314718055994531f

// 5-slot rolling row pipeline: slot = (row_off + 1) % 5.
// At iter i (output row r0+i): slots i,i+1,i+2 (mod 5) hold rows i-1,i,i+1;
// rows i+2,i+3 are in flight; after compute, row i+4 is issued into slot i%5.
template<bool INTERIOR>
__device__ __forceinline__ float band_loss(const float* __restrict__ sp,
                                           const float* __restrict__ op,
                                           int r0, bool eL, bool eR, int lane) {
  float sv[5][TC], ov[5][TC];
  float slv[5], olv[5], srv[5], orv[5];

  auto issue = [&](int slot, int i) {  // row = r0 + i
    const bool rv = INTERIOR || ((r0 + i) >= 0 && (r0 + i) < H);
    const long off = (long)i * W;
    if (rv) {
      const float4 a = *reinterpret_cast<const float4*>(sp + off);
      const float4 b = *reinterpret_cast<const float4*>(op + off);
      sv[slot][0] = a.x; sv[slot][1] = a.y; sv[slot][2] = a.z; sv[slot][3] = a.w;
      ov[slot][0] = b.x; ov[slot][1] = b.y; ov[slot][2] = b.z; ov[slot][3] = b.w;
      slv[slot] = eL ? sp[off - 1]  : 0.f;   // exec-masked: only lane 0
      olv[slot] = eL ? op[off - 1]  : 0.f;
      srv[slot] = eR ? sp[off + TC] : 0.f;   // only lane 63
      orv[slot] = eR ? op[off + TC] : 0.f;
    } else {
      #pragma unroll
      for (int k = 0; k < TC; ++k) { sv[slot][k] = 0.f; ov[slot][k] = 0.f; }
      slv[slot] = olv[slot] = srv[slot] = orv[slot] = 0.f;
    }
  };

  issue(0, -1); issue(1, 0); issue(2, 1); issue(3, 2); issue(4, 3);

  float acc = 0.f;
  #pragma unroll
  for (int i = 0; i < R; ++i) {
    const int A = i % 5, B = (i + 1) % 5, C = (i + 2) % 5;

    float cs[TC], co[TC];
    #pragma unroll
    for (int k = 0; k < TC; ++k) {
      cs[k] = sv[A][k] + sv[B][k] + sv[C][k];
      co[k] = ov[A][k] + ov[B][k] + ov[C][k];
    }
    const float eLs = slv[A] + slv[B] + slv[C];
    const float eLo = olv[A] + olv[B] + olv[C];
    const float eRs = srv[A] + srv[B] + srv[C];
    const float eRo = orv[A] + orv[B] + orv[C];

    // halo column sums from neighbor lanes; lanes 0/63 use their global-loaded values
    float csL = __shfl_up(cs[TC-1], 1, 64);  if (lane == 0)  csL = eLs;
    float coL = __shfl_up(co[TC-1], 1, 64);  if (lane == 0)  coL = eLo;
    float csR = __shfl_down(cs[0], 1, 64);   if (lane == 63) csR = eRs;
    float coR = __shfl_down(co[0], 1, 64);   if (lane == 63) coR = eRo;

    #pragma unroll
    for (int k = 0; k < TC; ++k) {
      const float cl  = (k == 0)    ? csL : cs[k-1];
      const float cr  = (k == TC-1) ? csR : cs[k+1];
      const float nsS = cl + cs[k] + cr - sv[B][k];    // 8-neighbor sum of seg
      const float col = (k == 0)    ? coL : co[k-1];
      const float cor = (k == TC-1) ? coR : co[k+1];
      const float nsO = col + co[k] + cor - ov[B][k];  // 8-neighbor sum of out
      const float w1 = 9.f - nsS;                      // sig_seg_1
      const float m0 = 1.f + nsO;                      // sig_out_0
      const float s = sv[B][k], o = ov[B][k];
      acc += w1 * s * __log2f(o + 1e-5f) + m0 * (1.f - s) * __log2f(1.00001f - o);
    }

    if (i + 4 <= R) issue(A, i + 4);   // rows r0+4 .. r0+R into the just-freed slot
  }
  return acc;
}

__global__ __launch_bounds__(TPB, 4)
void wbce_kernel(const float* __restrict__ outp, const float* __restrict__ segp,
                 float* __restrict__ dsum) {
  const int t     = threadIdx.x;
  const int strip = blockIdx.x;
  const int band  = blockIdx.y;
  const int r0    = band * R;
  const int c0    = strip * STRIP + t * TC;
  const int lane  = t & 63;
  const bool eL   = (lane == 0)  && (c0 > 0);
  const bool eR   = (lane == 63) && (c0 + TC < W);

  const float* sp = segp + (size_t)r0 * W + c0;
  const float* op = outp + (size_t)r0 * W + c0;

  float acc;
  if (band > 0 && band < NBAND - 1) acc = band_loss<true >(sp, op, r0, eL, eR, lane);
  else                              acc = band_loss<false>(sp, op, r0, eL, eR, lane);

  // wave reduce (64 lanes)
  #pragma unroll
  for (int off = 32; off > 0; off >>= 1) acc += __shfl_down(acc, off, 64);

  __shared__ float wsum[TPB / 64];
  if ((t & 63) == 0) wsum[t >> 6] = acc;
  __syncthreads();
  if (t == 0) {
    const float ssum = wsum[0] + wsum[1] + wsum[2] + wsum[3];
    atomicAdd(dsum, ssum * (-LN2 / ((float)H * (float)W)));  // loss = -mean, log2->ln
  }
}

extern "C" void kernel_launch(void* const* d_in, const int* in_sizes, int n_in,
                              void* d_out, int out_size, void* d_ws, size_t ws_size,
                              hipStream_t stream) {
  const float* outp = (const float*)d_in[0];  // out_image
  const float* segp = (const float*)d_in[1];  // segment_image
  float* o = (float*)d_out;
  hipMemsetAsync(o, 0, sizeof(float), stream);   // graph-capturable; re-zero every call
  wbce_kernel<<<dim3(NSTRIP, NBAND), TPB, 0, stream>>>(outp, segp, o);
}